// Round 4
// baseline (1618.403 us; speedup 1.0000x reference)
//
#include <hip/hip_runtime.h>
#include <stdint.h>

#define NLV 8
#define KCB 1024
#define DM  512
#define NTOK (8*4096)
#define BETA 0.00390625f   // 2^-8 bias: keeps lo-planes f16-normal, folds into c2'

typedef _Float16 f16;
typedef f16  f16x4 __attribute__((ext_vector_type(4)));
typedef f16  f16x8 __attribute__((ext_vector_type(8)));
typedef float f32x4 __attribute__((ext_vector_type(4)));

typedef __attribute__((address_space(1))) const unsigned int* as1p;
typedef __attribute__((address_space(3))) unsigned int*       as3p;
__device__ __forceinline__ void gll16(const void* g, void* l) {
    __builtin_amdgcn_global_load_lds((as1p)g, (as3p)l, 16, 0, 0);
}

// ---------------- c2' precompute: sum(c^2) + 2*beta*sum(f16(c)) ----------------
__global__ void c2_kernel(const float* __restrict__ cbs, float* __restrict__ c2) {
    int row  = blockIdx.x;
    int lane = threadIdx.x;
    const float4* p4 = (const float4*)(cbs + (size_t)row * DM);
    float4 a = p4[lane];
    float4 b = p4[lane + 64];
    float s = a.x*a.x + a.y*a.y + a.z*a.z + a.w*a.w
            + b.x*b.x + b.y*b.y + b.z*b.z + b.w*b.w;
    float t = (float)(f16)a.x + (float)(f16)a.y + (float)(f16)a.z + (float)(f16)a.w
            + (float)(f16)b.x + (float)(f16)b.y + (float)(f16)b.z + (float)(f16)b.w;
    #pragma unroll
    for (int off = 32; off > 0; off >>= 1) {
        s += __shfl_down(s, off, 64);
        t += __shfl_down(t, off, 64);
    }
    if (lane == 0) c2[row] = s + 2.0f * BETA * t;
}

// ---------------- hi/lo split with bias ----------------
__global__ void split_kernel(const float* __restrict__ src,
                             f16* __restrict__ hi, f16* __restrict__ lo) {
    size_t i = (size_t)blockIdx.x * 256 + threadIdx.x;   // float4 index
    float4 v = ((const float4*)src)[i];
    f16x4 h, l;
    h.x = (f16)v.x; l.x = (f16)((v.x - (float)h.x) + BETA);
    h.y = (f16)v.y; l.y = (f16)((v.y - (float)h.y) + BETA);
    h.z = (f16)v.z; l.z = (f16)((v.z - (float)h.z) + BETA);
    h.w = (f16)v.w; l.w = (f16)((v.w - (float)h.w) + BETA);
    ((f16x4*)hi)[i] = h;
    ((f16x4*)lo)[i] = l;
}

// ---------------- main MFMA level kernel ----------------
// 512 threads = 8 waves (2 M-strips of 32 x 4 N-strips of 64). M=64 tokens/block,
// grid 512 blocks = 2 blocks/CU (LDS 64 KB, VGPR<=128) -> decoupled barriers.
// LDS holds B only (double-buffered 2x32KB); A frags load global->VGPR, ping-pong
// prefetched one kstep ahead. Single acc chain via beta-biased lo planes.
#define MBT  64
#define NCH  256
#define KS   32
#define NTHR 512

__global__ __launch_bounds__(NTHR, 4)
void rvq_mfma(const float* __restrict__ xin, float* __restrict__ qout,
              const float* __restrict__ cbs,
              const f16* __restrict__ Bhi, const f16* __restrict__ Blo,
              f16* __restrict__ Ahi, f16* __restrict__ Alo,
              const float* __restrict__ c2g, float* __restrict__ idxout,
              int lvl, int is_last)
{
    __shared__ char smem[65536];         // 2 x (Bh 16KB | Bl 16KB)
    const int tid  = threadIdx.x;
    const int lane = tid & 63;
    const int wid  = tid >> 6;           // 0..7
    const int wm   = wid >> 2;           // 0..1  M strip (32 tokens)
    const int wn   = wid & 3;            // 0..3  N strip (64 codebooks)
    const int tx   = lane & 15;
    const int q    = lane >> 4;
    const size_t tok0 = (size_t)blockIdx.x * MBT;

    const f16*   Bh_l = Bhi + (size_t)lvl * KCB * DM;
    const f16*   Bl_l = Blo + (size_t)lvl * KCB * DM;
    const float* c2l  = c2g + lvl * KCB;
    const float* cbl  = cbs + (size_t)lvl * KCB * DM;

    // B staging: slot s = tid (rows 0..127) and tid+512 (rows 128..255);
    // row = s>>2, pos = s&3, fetched granule g = pos ^ ((row>>1)&3)
    const int srow = tid >> 2;
    const int sg   = (tid & 3) ^ ((srow >> 1) & 3);
    auto stageB = [&](char* buf, int cb0, int k0) {
        const int ko = k0 + sg * 8;
        const size_t g0 = (size_t)(cb0 + srow) * DM + ko;
        const size_t g1 = g0 + (size_t)128 * DM;
        char* l0 = buf + wid * 1024;     // wave-uniform base
        gll16(&Bh_l[g0], l0);
        gll16(&Bh_l[g1], l0 + 8192);
        gll16(&Bl_l[g0], l0 + 16384);
        gll16(&Bl_l[g1], l0 + 16384 + 8192);
    };

    // B fragment read offsets (bytes within a plane)
    int boff[4];
    #pragma unroll
    for (int j = 0; j < 4; ++j) {
        int row = wn * 64 + j * 16 + tx;
        boff[j] = row * 64 + (q ^ ((tx >> 1) & 3)) * 16;
    }

    // A direct fragment base (row tok0 + wm*32 + i*16 + tx, col q*8)
    const f16* aH = Ahi + (tok0 + wm * 32 + tx) * (size_t)DM + q * 8;
    const f16* aL = Alo + (tok0 + wm * 32 + tx) * (size_t)DM + q * 8;

    float bestv[8];
    int   besti[8];
    #pragma unroll
    for (int t = 0; t < 8; ++t) { bestv[t] = 3.4e38f; besti[t] = 0; }

    // preload A(k=0) set 0; stage B(ch0, k0) into buf0
    f16x8 Ah[2][2], Al[2][2];
    #pragma unroll
    for (int i = 0; i < 2; ++i) {
        Ah[0][i] = *(const f16x8*)(aH + i * 16 * DM);
        Al[0][i] = *(const f16x8*)(aL + i * 16 * DM);
    }
    stageB(smem, 0, 0);

    for (int ch = 0; ch < KCB / NCH; ++ch) {
        const int cb0 = ch * NCH;
        f32x4 acc[2][4];
        #pragma unroll
        for (int i = 0; i < 2; ++i)
            #pragma unroll
            for (int j = 0; j < 4; ++j) acc[i][j] = (f32x4)0.0f;

        for (int kh = 0; kh < 8; ++kh) {
            #pragma unroll
            for (int u = 0; u < 2; ++u) {
                const int gk = ch * 16 + kh * 2 + u;   // global kstep 0..63
                char* bb = smem + u * 32768;
                char* bn = smem + (u ^ 1) * 32768;
                __syncthreads();                       // drains prev prefetch
                if (gk + 1 < 64)
                    stageB(bn, ((gk + 1) >> 4) * NCH, ((gk + 1) & 15) * KS);

                f16x8 bh[4], bl[4];
                #pragma unroll
                for (int j = 0; j < 4; ++j) {
                    bh[j] = *(const f16x8*)(bb + boff[j]);
                    bl[j] = *(const f16x8*)(bb + 16384 + boff[j]);
                }
                // A ping-pong prefetch for next kstep (wraps to 0 at chunk end)
                const int nk = ((gk + 1) & 15) * KS;
                #pragma unroll
                for (int i = 0; i < 2; ++i) {
                    Ah[u ^ 1][i] = *(const f16x8*)(aH + i * 16 * DM + nk);
                    Al[u ^ 1][i] = *(const f16x8*)(aL + i * 16 * DM + nk);
                }
                #pragma unroll
                for (int j = 0; j < 4; ++j)
                    #pragma unroll
                    for (int i = 0; i < 2; ++i) {
                        acc[i][j] = __builtin_amdgcn_mfma_f32_16x16x32_f16(Ah[u][i], bh[j], acc[i][j], 0, 0, 0);
                        acc[i][j] = __builtin_amdgcn_mfma_f32_16x16x32_f16(Ah[u][i], bl[j], acc[i][j], 0, 0, 0);
                        acc[i][j] = __builtin_amdgcn_mfma_f32_16x16x32_f16(Al[u][i], bh[j], acc[i][j], 0, 0, 0);
                    }
            }
        }

        // chunk argmin epilogue: score = c2'[n] - 2*acc  (token-const terms dropped)
        #pragma unroll
        for (int j = 0; j < 4; ++j) {
            int n = cb0 + wn * 64 + j * 16 + tx;
            float c2v = c2l[n];
            #pragma unroll
            for (int i = 0; i < 2; ++i)
                #pragma unroll
                for (int r = 0; r < 4; ++r) {
                    float s = fmaf(-2.f, acc[i][j][r], c2v);
                    int t = i * 4 + r;
                    if (s < bestv[t]) { bestv[t] = s; besti[t] = n; }
                }
        }
    }

    // cross-lane argmin over tx (16 lanes; same q -> same token rows)
    #pragma unroll
    for (int t = 0; t < 8; ++t) {
        float v = bestv[t]; int bi = besti[t];
        #pragma unroll
        for (int off = 1; off < 16; off <<= 1) {
            float ov = __shfl_xor(v, off, 64);
            int   oi = __shfl_xor(bi, off, 64);
            if (ov < v || (ov == v && oi < bi)) { v = ov; bi = oi; }
        }
        bestv[t] = v; besti[t] = bi;
    }

    // cross-wave reduce over wn; overlay on buf0 (all frag reads retired)
    float* redV = (float*)smem;            // [2 wm][4 wn][32 m]  1 KB
    int*   redI = (int*)(smem + 1024);     // 1 KB
    int*   kbst = (int*)(smem + 2048);     // 64 ints
    __syncthreads();
    if (tx == 0) {
        #pragma unroll
        for (int i = 0; i < 2; ++i)
            #pragma unroll
            for (int r = 0; r < 4; ++r) {
                int m = i * 16 + q * 4 + r;
                redV[(wm * 4 + wn) * 32 + m] = bestv[i * 4 + r];
                redI[(wm * 4 + wn) * 32 + m] = besti[i * 4 + r];
            }
    }
    __syncthreads();
    if (tid < MBT) {
        int strip = tid >> 5, m = tid & 31;
        float bv = redV[(strip * 4) * 32 + m];
        int   bi = redI[(strip * 4) * 32 + m];
        #pragma unroll
        for (int w = 1; w < 4; ++w) {
            float v  = redV[(strip * 4 + w) * 32 + m];
            int   ii = redI[(strip * 4 + w) * 32 + m];
            if (v < bv || (v == bv && ii < bi)) { bv = v; bi = ii; }
        }
        kbst[tid] = bi;
        idxout[(tok0 + tid) * NLV + lvl] = (float)bi;
    }
    __syncthreads();

    // residual update on biased hi/lo planes: r = hi + (lo - beta) - c
    for (int it = 0; it < 8; ++it) {
        int e  = it * NTHR + tid;          // 64 tok x 64 granules of 8
        int t  = e >> 6, d8 = e & 63;
        size_t go = (tok0 + t) * (size_t)DM + d8 * 8;
        f16x8 h8 = *(const f16x8*)&Ahi[go];
        f16x8 l8 = *(const f16x8*)&Alo[go];
        const float* cp = &cbl[(size_t)kbst[t] * DM + d8 * 8];
        float4 c0 = *(const float4*)cp;
        float4 c1 = *(const float4*)(cp + 4);
        float r[8];
        r[0] = (float)h8[0] + ((float)l8[0] - BETA) - c0.x;
        r[1] = (float)h8[1] + ((float)l8[1] - BETA) - c0.y;
        r[2] = (float)h8[2] + ((float)l8[2] - BETA) - c0.z;
        r[3] = (float)h8[3] + ((float)l8[3] - BETA) - c0.w;
        r[4] = (float)h8[4] + ((float)l8[4] - BETA) - c1.x;
        r[5] = (float)h8[5] + ((float)l8[5] - BETA) - c1.y;
        r[6] = (float)h8[6] + ((float)l8[6] - BETA) - c1.z;
        r[7] = (float)h8[7] + ((float)l8[7] - BETA) - c1.w;
        if (is_last) {
            float4 x0 = *(const float4*)&xin[go];
            float4 x1 = *(const float4*)&xin[go + 4];
            float4 q0 = make_float4(x0.x - r[0], x0.y - r[1], x0.z - r[2], x0.w - r[3]);
            float4 q1 = make_float4(x1.x - r[4], x1.y - r[5], x1.z - r[6], x1.w - r[7]);
            *(float4*)&qout[go]     = q0;
            *(float4*)&qout[go + 4] = q1;
        } else {
            f16x8 h, l;
            #pragma unroll
            for (int k = 0; k < 8; ++k) {
                h[k] = (f16)r[k];
                l[k] = (f16)((r[k] - (float)h[k]) + BETA);
            }
            *(f16x8*)&Ahi[go] = h;
            *(f16x8*)&Alo[go] = l;
        }
    }
}

// =================== launch ===================
extern "C" void kernel_launch(void* const* d_in, const int* in_sizes, int n_in,
                              void* d_out, int out_size, void* d_ws, size_t ws_size,
                              hipStream_t stream) {
    const float* x   = (const float*)d_in[0];   // [8,4096,512]
    const float* cbs = (const float*)d_in[1];   // [8,1024,512]
    float* qout   = (float*)d_out;                       // [8,4096,512]
    float* idxout = qout + (size_t)NTOK * DM;            // [8,4096,8] as float

    const size_t B_ELE = (size_t)NLV * KCB * DM;   // 4,194,304
    const size_t A_ELE = (size_t)NTOK * DM;        // 16,777,216

    f16* Bhi = (f16*)d_ws;
    f16* Blo = Bhi + B_ELE;
    f16* Ahi = Blo + B_ELE;
    f16* Alo = Ahi + A_ELE;
    float* c2 = (float*)(Alo + A_ELE);

    split_kernel<<<(int)(B_ELE / 4 / 256), 256, 0, stream>>>(cbs, Bhi, Blo);
    split_kernel<<<(int)(A_ELE / 4 / 256), 256, 0, stream>>>(x, Ahi, Alo);
    c2_kernel<<<NLV * KCB, 64, 0, stream>>>(cbs, c2);

    const int nblocks = NTOK / MBT;  // 512 -> 2 blocks/CU
    for (int l = 0; l < NLV; ++l) {
        rvq_mfma<<<nblocks, NTHR, 0, stream>>>(x, qout, cbs,
                                               Bhi, Blo, Ahi, Alo, c2, idxout,
                                               l, (l == NLV - 1) ? 1 : 0);
    }
}

// Round 5
// 1149.714 us; speedup vs baseline: 1.4077x; 1.4077x over previous
//
#include <hip/hip_runtime.h>
#include <stdint.h>

#define NLV 8
#define KCB 1024
#define DM  512
#define NTOK (8*4096)
#define BETA 0.00390625f   // 2^-8 bias keeps lo-planes f16-normal; folds into c2'

typedef _Float16 f16;
typedef f16  f16x4 __attribute__((ext_vector_type(4)));
typedef f16  f16x8 __attribute__((ext_vector_type(8)));
typedef float f32x4 __attribute__((ext_vector_type(4)));

typedef __attribute__((address_space(1))) const unsigned int* as1p;
typedef __attribute__((address_space(3))) unsigned int*       as3p;
__device__ __forceinline__ void gll16(const void* g, void* l) {
    __builtin_amdgcn_global_load_lds((as1p)g, (as3p)l, 16, 0, 0);
}

// ---------------- c2' precompute: sum(c^2) + 2*beta*sum(f16(c)) ----------------
__global__ void c2_kernel(const float* __restrict__ cbs, float* __restrict__ c2) {
    int row  = blockIdx.x;
    int lane = threadIdx.x;
    const float4* p4 = (const float4*)(cbs + (size_t)row * DM);
    float4 a = p4[lane];
    float4 b = p4[lane + 64];
    float s = a.x*a.x + a.y*a.y + a.z*a.z + a.w*a.w
            + b.x*b.x + b.y*b.y + b.z*b.z + b.w*b.w;
    float t = (float)(f16)a.x + (float)(f16)a.y + (float)(f16)a.z + (float)(f16)a.w
            + (float)(f16)b.x + (float)(f16)b.y + (float)(f16)b.z + (float)(f16)b.w;
    #pragma unroll
    for (int off = 32; off > 0; off >>= 1) {
        s += __shfl_down(s, off, 64);
        t += __shfl_down(t, off, 64);
    }
    if (lane == 0) c2[row] = s + 2.0f * BETA * t;
}

// ---------------- hi/lo split with bias ----------------
__global__ void split_kernel(const float* __restrict__ src,
                             f16* __restrict__ hi, f16* __restrict__ lo) {
    size_t i = (size_t)blockIdx.x * 256 + threadIdx.x;   // float4 index
    float4 v = ((const float4*)src)[i];
    f16x4 h, l;
    h.x = (f16)v.x; l.x = (f16)((v.x - (float)h.x) + BETA);
    h.y = (f16)v.y; l.y = (f16)((v.y - (float)h.y) + BETA);
    h.z = (f16)v.z; l.z = (f16)((v.z - (float)h.z) + BETA);
    h.w = (f16)v.w; l.w = (f16)((v.w - (float)h.w) + BETA);
    ((f16x4*)hi)[i] = h;
    ((f16x4*)lo)[i] = l;
}

// ---------------- main MFMA level kernel ----------------
// 256 threads = 4 waves, each wave = one 64-cb N-strip; M=64 tokens/block.
// Grid 512 blocks -> 2 blocks/CU (LDS 80 KB/block, VGPR cap 256 via (256,2)).
// Two blocks per CU decouple the per-kstep barrier: while one block drains
// its prefetch at s_barrier, the other block's wave on the same SIMD issues
// MFMA (m114 co-scheduling). Double-buffered LDS, one barrier per kstep,
// cross-buffer global_load_lds prefetch. XOR granule swizzle -> 0 conflicts.
// Single acc chain via beta-biased lo planes (validated round 4).
#define MBT  64
#define NCH  256
#define KS   32
#define NTHR 256
#define BUFB 40960   // Ah 4K | Al 4K | Bh 16K | Bl 16K

__global__ __launch_bounds__(NTHR, 2)
void rvq_mfma(const float* __restrict__ xin, float* __restrict__ qout,
              const float* __restrict__ cbs,
              const f16* __restrict__ Bhi, const f16* __restrict__ Blo,
              f16* __restrict__ Ahi, f16* __restrict__ Alo,
              const float* __restrict__ c2g, float* __restrict__ idxout,
              int lvl, int is_last)
{
    __shared__ char smem[2 * BUFB];      // 81920 B -> exactly 2 blocks/CU
    const int tid  = threadIdx.x;
    const int lane = tid & 63;
    const int wn   = tid >> 6;           // 0..3  N strip (64 codebooks)
    const int tx   = lane & 15;
    const int q    = lane >> 4;
    const size_t tok0 = (size_t)blockIdx.x * MBT;

    const f16*   Bh_l = Bhi + (size_t)lvl * KCB * DM;
    const f16*   Bl_l = Blo + (size_t)lvl * KCB * DM;
    const float* c2l  = c2g + lvl * KCB;
    const float* cbl  = cbs + (size_t)lvl * KCB * DM;

    // staging: thread tid covers row srow, granule-position tid&3; fetched
    // granule g = pos ^ ((row>>1)&3). LDS slot = tid*16 within each plane.
    const int srow = tid >> 2;                       // 0..63
    const int sg   = (tid & 3) ^ ((srow >> 1) & 3);
    const int rsw  = q ^ ((tx >> 1) & 3);            // read-side granule pos

    auto stage = [&](char* buf, int cb0, int k0) {
        const int ko = k0 + sg * 8;
        char* wb = buf + wn * 1024;                  // wave-uniform base
        const size_t ga = (tok0 + srow) * (size_t)DM + ko;
        gll16(&Ahi[ga], wb);
        gll16(&Alo[ga], wb + 4096);
        #pragma unroll
        for (int i = 0; i < 4; ++i) {
            const size_t gb = (size_t)(cb0 + 64 * i + srow) * DM + ko;
            gll16(&Bh_l[gb], wb +  8192 + 4096 * i);
            gll16(&Bl_l[gb], wb + 24576 + 4096 * i);
        }
    };

    // fragment byte offsets within planes
    int aoff[4], boff[4];
    #pragma unroll
    for (int i = 0; i < 4; ++i) aoff[i] = (i * 16 + tx) * 64 + rsw * 16;
    #pragma unroll
    for (int j = 0; j < 4; ++j) boff[j] = (wn * 64 + j * 16 + tx) * 64 + rsw * 16;

    float bestv[16];
    int   besti[16];
    #pragma unroll
    for (int t = 0; t < 16; ++t) { bestv[t] = 3.4e38f; besti[t] = 0; }

    stage(smem, 0, 0);   // gk=0 -> buf0

    for (int ch = 0; ch < KCB / NCH; ++ch) {
        f32x4 acc[4][4];
        #pragma unroll
        for (int i = 0; i < 4; ++i)
            #pragma unroll
            for (int j = 0; j < 4; ++j) acc[i][j] = (f32x4)0.0f;

        for (int kk = 0; kk < 16; ++kk) {
            const int gk = ch * 16 + kk;             // 0..63
            char* bb = smem + (gk & 1) * BUFB;
            char* bn = smem + ((gk & 1) ^ 1) * BUFB;
            __syncthreads();                         // drains prefetch from gk-1
            if (gk + 1 < 64)
                stage(bn, ((gk + 1) >> 4) * NCH, ((gk + 1) & 15) * KS);

            f16x8 ah[4], al[4], bh[4], bl[4];
            #pragma unroll
            for (int i = 0; i < 4; ++i) {
                ah[i] = *(const f16x8*)(bb +        aoff[i]);
                al[i] = *(const f16x8*)(bb + 4096 + aoff[i]);
            }
            #pragma unroll
            for (int j = 0; j < 4; ++j) {
                bh[j] = *(const f16x8*)(bb +  8192 + boff[j]);
                bl[j] = *(const f16x8*)(bb + 24576 + boff[j]);
            }
            // three passes as separate sweeps: same-acc dependency distance 16
            #pragma unroll
            for (int j = 0; j < 4; ++j)
                #pragma unroll
                for (int i = 0; i < 4; ++i)
                    acc[i][j] = __builtin_amdgcn_mfma_f32_16x16x32_f16(ah[i], bh[j], acc[i][j], 0, 0, 0);
            #pragma unroll
            for (int j = 0; j < 4; ++j)
                #pragma unroll
                for (int i = 0; i < 4; ++i)
                    acc[i][j] = __builtin_amdgcn_mfma_f32_16x16x32_f16(ah[i], bl[j], acc[i][j], 0, 0, 0);
            #pragma unroll
            for (int j = 0; j < 4; ++j)
                #pragma unroll
                for (int i = 0; i < 4; ++i)
                    acc[i][j] = __builtin_amdgcn_mfma_f32_16x16x32_f16(al[i], bh[j], acc[i][j], 0, 0, 0);
        }

        // chunk argmin epilogue (C/D: col=lane&15, row=(lane>>4)*4+reg)
        const int cb0 = ch * NCH;
        #pragma unroll
        for (int j = 0; j < 4; ++j) {
            int n = cb0 + wn * 64 + j * 16 + tx;
            float c2v = c2l[n];
            #pragma unroll
            for (int i = 0; i < 4; ++i)
                #pragma unroll
                for (int r = 0; r < 4; ++r) {
                    float s = fmaf(-2.f, acc[i][j][r], c2v);
                    int t = i * 4 + r;
                    if (s < bestv[t]) { bestv[t] = s; besti[t] = n; }
                }
        }
    }

    // cross-lane argmin over tx (16 lanes; same q -> same token rows)
    #pragma unroll
    for (int t = 0; t < 16; ++t) {
        float v = bestv[t]; int bi = besti[t];
        #pragma unroll
        for (int off = 1; off < 16; off <<= 1) {
            float ov = __shfl_xor(v, off, 64);
            int   oi = __shfl_xor(bi, off, 64);
            if (ov < v || (ov == v && oi < bi)) { v = ov; bi = oi; }
        }
        bestv[t] = v; besti[t] = bi;
    }

    // cross-wave reduce over the 4 wn strips; overlay on buf0 (reads retired)
    float* redV = (float*)smem;            // [4 wn][64 m]  1 KB
    int*   redI = (int*)(smem + 1024);     // 1 KB
    int*   kbst = (int*)(smem + 2048);     // 64 ints
    __syncthreads();
    if (tx == 0) {
        #pragma unroll
        for (int i = 0; i < 4; ++i)
            #pragma unroll
            for (int r = 0; r < 4; ++r) {
                int m = i * 16 + q * 4 + r;
                redV[wn * 64 + m] = bestv[i * 4 + r];
                redI[wn * 64 + m] = besti[i * 4 + r];
            }
    }
    __syncthreads();
    if (tid < MBT) {
        float bv = redV[tid]; int bi = redI[tid];
        #pragma unroll
        for (int w = 1; w < 4; ++w) {
            float v  = redV[w * 64 + tid];
            int   ii = redI[w * 64 + tid];
            if (v < bv || (v == bv && ii < bi)) { bv = v; bi = ii; }
        }
        kbst[tid] = bi;
        idxout[(tok0 + tid) * NLV + lvl] = (float)bi;
    }
    __syncthreads();

    // residual update on biased hi/lo planes: r = hi + (lo - beta) - c
    #pragma unroll 4
    for (int it = 0; it < 16; ++it) {
        int e  = it * NTHR + tid;          // 64 tok x 64 granules of 8
        int t  = e >> 6, d8 = e & 63;
        size_t go = (tok0 + t) * (size_t)DM + d8 * 8;
        f16x8 h8 = *(const f16x8*)&Ahi[go];
        f16x8 l8 = *(const f16x8*)&Alo[go];
        const float* cp = &cbl[(size_t)kbst[t] * DM + d8 * 8];
        float4 c0 = *(const float4*)cp;
        float4 c1 = *(const float4*)(cp + 4);
        float r[8];
        r[0] = (float)h8[0] + ((float)l8[0] - BETA) - c0.x;
        r[1] = (float)h8[1] + ((float)l8[1] - BETA) - c0.y;
        r[2] = (float)h8[2] + ((float)l8[2] - BETA) - c0.z;
        r[3] = (float)h8[3] + ((float)l8[3] - BETA) - c0.w;
        r[4] = (float)h8[4] + ((float)l8[4] - BETA) - c1.x;
        r[5] = (float)h8[5] + ((float)l8[5] - BETA) - c1.y;
        r[6] = (float)h8[6] + ((float)l8[6] - BETA) - c1.z;
        r[7] = (float)h8[7] + ((float)l8[7] - BETA) - c1.w;
        if (is_last) {
            float4 x0 = *(const float4*)&xin[go];
            float4 x1 = *(const float4*)&xin[go + 4];
            float4 q0 = make_float4(x0.x - r[0], x0.y - r[1], x0.z - r[2], x0.w - r[3]);
            float4 q1 = make_float4(x1.x - r[4], x1.y - r[5], x1.z - r[6], x1.w - r[7]);
            *(float4*)&qout[go]     = q0;
            *(float4*)&qout[go + 4] = q1;
        } else {
            f16x8 h, l;
            #pragma unroll
            for (int k = 0; k < 8; ++k) {
                h[k] = (f16)r[k];
                l[k] = (f16)((r[k] - (float)h[k]) + BETA);
            }
            *(f16x8*)&Ahi[go] = h;
            *(f16x8*)&Alo[go] = l;
        }
    }
}

// =================== launch ===================
extern "C" void kernel_launch(void* const* d_in, const int* in_sizes, int n_in,
                              void* d_out, int out_size, void* d_ws, size_t ws_size,
                              hipStream_t stream) {
    const float* x   = (const float*)d_in[0];   // [8,4096,512]
    const float* cbs = (const float*)d_in[1];   // [8,1024,512]
    float* qout   = (float*)d_out;                       // [8,4096,512]
    float* idxout = qout + (size_t)NTOK * DM;            // [8,4096,8] as float

    const size_t B_ELE = (size_t)NLV * KCB * DM;   // 4,194,304
    const size_t A_ELE = (size_t)NTOK * DM;        // 16,777,216

    f16* Bhi = (f16*)d_ws;
    f16* Blo = Bhi + B_ELE;
    f16* Ahi = Blo + B_ELE;
    f16* Alo = Ahi + A_ELE;
    float* c2 = (float*)(Alo + A_ELE);

    split_kernel<<<(int)(B_ELE / 4 / 256), 256, 0, stream>>>(cbs, Bhi, Blo);
    split_kernel<<<(int)(A_ELE / 4 / 256), 256, 0, stream>>>(x, Ahi, Alo);
    c2_kernel<<<NLV * KCB, 64, 0, stream>>>(cbs, c2);

    const int nblocks = NTOK / MBT;  // 512 -> 2 blocks/CU
    for (int l = 0; l < NLV; ++l) {
        rvq_mfma<<<nblocks, NTHR, 0, stream>>>(x, qout, cbs,
                                               Bhi, Blo, Ahi, Alo, c2, idxout,
                                               l, (l == NLV - 1) ? 1 : 0);
    }
}